// Round 10
// baseline (4474.022 us; speedup 1.0000x reference)
//
#include <hip/hip_runtime.h>
#include <math.h>

#define B_   512
#define T_   2048
#define H_   64
#define NS_  32
#define HH_  128   // 2H
#define G4_  256   // 4H
#define EPSF 1e-5f

typedef _Float16 half8 __attribute__((ext_vector_type(8)));
typedef _Float16 h4   __attribute__((ext_vector_type(4)));
typedef float    f32x4 __attribute__((ext_vector_type(4)));

__device__ __forceinline__ float gelu_f(float x) {
    return 0.5f * x * (1.0f + erff(x * 0.70710678118654752440f));
}
__device__ __forceinline__ float sigmoid_f(float x) {
    return 1.0f / (1.0f + __expf(-x));
}
__device__ __forceinline__ float tanh_f(float x) {
    return 1.0f - 2.0f / (__expf(2.0f * x) + 1.0f);
}

// ---------------------------------------------------------------------------
// Input projection -> packed fp16 x-sequence  seqh[B][T][64]
// ---------------------------------------------------------------------------
__global__ void __launch_bounds__(256) inproj_kernel(
    const float* __restrict__ sensors, const float* __restrict__ W1,
    const float* __restrict__ b1, const float* __restrict__ g1,
    const float* __restrict__ bb1, const float* __restrict__ W2,
    const float* __restrict__ b2, _Float16* __restrict__ seqh)
{
    __shared__ __align__(16) float W1l[NS_ * H_];
    __shared__ __align__(16) float W2l[H_ * H_];
    __shared__ float p1[H_], p2[H_], p3[H_], p4[H_];
    const int tid = threadIdx.x;
    {
        const float4* s1 = (const float4*)W1;
        float4* d1 = (float4*)W1l;
        for (int i = tid; i < NS_ * H_ / 4; i += 256) d1[i] = s1[i];
        const float4* s2 = (const float4*)W2;
        float4* d2 = (float4*)W2l;
        for (int i = tid; i < H_ * H_ / 4; i += 256) d2[i] = s2[i];
        if (tid < H_) { p1[tid] = b1[tid]; p2[tid] = g1[tid];
                        p3[tid] = bb1[tid]; p4[tid] = b2[tid]; }
    }
    __syncthreads();

    const long idx = (long)blockIdx.x * 256 + tid;
    const float* srow = sensors + idx * NS_;
    float sv[NS_];
    #pragma unroll
    for (int q = 0; q < NS_ / 4; ++q) {
        float4 v = *(const float4*)&srow[q * 4];
        sv[q*4+0] = v.x; sv[q*4+1] = v.y; sv[q*4+2] = v.z; sv[q*4+3] = v.w;
    }
    float t1[H_];
    #pragma unroll
    for (int jb = 0; jb < H_ / 4; ++jb) {
        float ax = p1[jb*4+0], ay = p1[jb*4+1], az = p1[jb*4+2], aw = p1[jb*4+3];
        #pragma unroll
        for (int k = 0; k < NS_; ++k) {
            float4 w = *(const float4*)&W1l[k * H_ + jb * 4];
            ax += sv[k]*w.x; ay += sv[k]*w.y; az += sv[k]*w.z; aw += sv[k]*w.w;
        }
        t1[jb*4+0] = ax; t1[jb*4+1] = ay; t1[jb*4+2] = az; t1[jb*4+3] = aw;
    }
    float mean = 0.f;
    #pragma unroll
    for (int j = 0; j < H_; ++j) mean += t1[j];
    mean *= (1.0f / H_);
    float var = 0.f;
    #pragma unroll
    for (int j = 0; j < H_; ++j) { float d = t1[j] - mean; var += d * d; }
    var *= (1.0f / H_);
    const float inv = rsqrtf(var + EPSF);
    #pragma unroll
    for (int j = 0; j < H_; ++j) {
        float nv = (t1[j] - mean) * inv * p2[j] + p3[j];
        t1[j] = gelu_f(nv);
    }
    _Float16* orow = seqh + idx * H_;
    for (int ob = 0; ob < H_ / 4; ++ob) {
        float ax = p4[ob*4+0], ay = p4[ob*4+1];
        float az = p4[ob*4+2], aw = p4[ob*4+3];
        #pragma unroll
        for (int j = 0; j < H_; ++j) {
            float4 w = *(const float4*)&W2l[j * H_ + ob * 4];
            ax += t1[j]*w.x; ay += t1[j]*w.y; az += t1[j]*w.z; aw += t1[j]*w.w;
        }
        h4 o; o[0] = (_Float16)ax; o[1] = (_Float16)ay;
              o[2] = (_Float16)az; o[3] = (_Float16)aw;
        *(h4*)&orow[ob * 4] = o;
    }
}

// ---------------------------------------------------------------------------
// Fused 4-layer pipelined LSTM via MFMA, single barrier per step.
//   256 blocks x 512 thr (8 waves = layer x col-half); block owns 2 rows.
//   nt-interleave: wave (l,h_) acc index a=2g+b -> global col
//   g*64 + h_*32 + b*16 + (lane&15); so lane L<16 holds ALL 4 gates for its
//   4 cells (u in {h_*32+L, h_*32+16+L}) x (row 0,1) -> in-lane nonlinearity,
//   no gate buffer, no cross-lane traffic. Bias pre-loaded into acc.
//   comb [parity][layer][row][128] fp16, linear; reads parity p, writes p^1
//   -> race-free with ONE __syncthreads per step.
//   A-frag: masked ds_read_b128 on the 8 lanes with arow<2; zeros elsewhere.
// ---------------------------------------------------------------------------
#define CIDX(p,l,r,k) ((((p)*4 + (l))*2 + (r))*128 + (k))

__global__ void __launch_bounds__(512, 2) lstm_fused_kernel(
    const float* __restrict__ Wg, const float* __restrict__ bg,
    const _Float16* __restrict__ xin,   // [B][T][64] fp16
    _Float16* __restrict__ h3f16,       // h3 out fp16 (if h3f32 null)
    float* __restrict__ h3f32)          // h3 out fp32 (preferred)
{
    __shared__ __align__(16) _Float16 combh[2 * 4 * 2 * HH_];   // 4 KB

    const int tid  = threadIdx.x;
    const int wv   = tid >> 6;
    const int lane = tid & 63;
    const int l    = wv >> 1;               // layer
    const int h_   = wv & 1;                // column half (unit group)
    const int L    = lane & 15;
    const int kgrp = lane >> 4;             // k-subgroup within fragment
    const int arow = L;                     // A-row this lane supplies

    // ---- weight B-fragments, nt-interleaved (once) ----
    const float* W = Wg + (size_t)l * HH_ * G4_;
    half8 wf[4][8];                          // [kt][a], a = 2*gate + b
    #pragma unroll
    for (int kt = 0; kt < 4; ++kt) {
        #pragma unroll
        for (int a = 0; a < 8; ++a) {
            const int col = (a >> 1) * 64 + h_ * 32 + (a & 1) * 16 + L;
            half8 f;
            #pragma unroll
            for (int j = 0; j < 8; ++j)
                f[j] = (_Float16)W[(kt * 32 + kgrp * 8 + j) * G4_ + col];
            wf[kt][a] = f;
        }
    }
    // per-acc bias (col depends on lane&15 only)
    float ba[8];
    #pragma unroll
    for (int a = 0; a < 8; ++a)
        ba[a] = bg[l * G4_ + (a >> 1) * 64 + h_ * 32 + (a & 1) * 16 + L];

    const int  u0 = h_ * 32 + L, u1 = u0 + 16;
    const long rb0 = ((long)(blockIdx.x * 2 + 0)) * T_ * H_;
    const long rb1 = ((long)(blockIdx.x * 2 + 1)) * T_ * H_;
    // x-prefetch duty (l==0 waves): all 64 lanes
    const int  xrow = lane >> 5;
    const int  xu   = h_ * 32 + (lane & 31);
    const long xbase = ((long)(blockIdx.x * 2 + xrow)) * T_ * H_ + xu;

    // ---- init: zero both parities, stage x(0) into parity 0 ----
    for (int i = tid; i < 2 * 4 * 2 * HH_ / 2; i += 512)
        ((float*)combh)[i] = 0.f;
    __syncthreads();
    if (l == 0) combh[CIDX(0, 0, xrow, xu)] = xin[xbase];
    __syncthreads();

    float c00 = 0.f, c01 = 0.f, c10 = 0.f, c11 = 0.f;

    for (int s = 0; s < T_ + 3; ++s) {
        const int p = s & 1, q = p ^ 1;
        const bool act = (s >= l) && (s - l < T_);

        _Float16 xnext = (_Float16)0.f;
        if (l == 0 && s + 1 < T_)            // issue early; hides under MFMAs
            xnext = xin[xbase + (long)(s + 1) * H_];

        if (act) {
            // A-fragments: only lanes with a real row read LDS
            half8 af[4];
            #pragma unroll
            for (int kt = 0; kt < 4; ++kt) {
                half8 v = {};
                if (arow < 2)
                    v = *(const half8*)&combh[CIDX(p, l, arow, kt * 32 + kgrp * 8)];
                af[kt] = v;
            }
            f32x4 acc[8];
            #pragma unroll
            for (int a = 0; a < 8; ++a)
                acc[a] = (f32x4){ba[a], ba[a], ba[a], ba[a]};
            #pragma unroll
            for (int kt = 0; kt < 4; ++kt) {
                #pragma unroll
                for (int a = 0; a < 8; ++a)
                    acc[a] = __builtin_amdgcn_mfma_f32_16x16x32_f16(
                        af[kt], wf[kt][a], acc[a], 0, 0, 0);
            }

            if (lane < 16) {
                const int t = s - l;
                // cell (u0,row0): gates a=0,2,4,6 reg0 ; (u0,row1): reg1
                // cell (u1,row0): gates a=1,3,5,7 reg0 ; (u1,row1): reg1
                const float i00 = sigmoid_f(acc[0][0]), f00 = sigmoid_f(acc[2][0]);
                const float g00 = tanh_f(acc[4][0]),    o00 = sigmoid_f(acc[6][0]);
                const float i01 = sigmoid_f(acc[0][1]), f01 = sigmoid_f(acc[2][1]);
                const float g01 = tanh_f(acc[4][1]),    o01 = sigmoid_f(acc[6][1]);
                const float i10 = sigmoid_f(acc[1][0]), f10 = sigmoid_f(acc[3][0]);
                const float g10 = tanh_f(acc[5][0]),    o10 = sigmoid_f(acc[7][0]);
                const float i11 = sigmoid_f(acc[1][1]), f11 = sigmoid_f(acc[3][1]);
                const float g11 = tanh_f(acc[5][1]),    o11 = sigmoid_f(acc[7][1]);
                c00 = f00 * c00 + i00 * g00;
                c01 = f01 * c01 + i01 * g01;
                c10 = f10 * c10 + i10 * g10;
                c11 = f11 * c11 + i11 * g11;
                const float h00 = o00 * tanh_f(c00);
                const float h01 = o01 * tanh_f(c01);
                const float h10 = o10 * tanh_f(c10);
                const float h11 = o11 * tanh_f(c11);
                const _Float16 q00 = (_Float16)h00, q01 = (_Float16)h01;
                const _Float16 q10 = (_Float16)h10, q11 = (_Float16)h11;
                // own h for next step
                combh[CIDX(q, l, 0, 64 + u0)] = q00;
                combh[CIDX(q, l, 1, 64 + u0)] = q01;
                combh[CIDX(q, l, 0, 64 + u1)] = q10;
                combh[CIDX(q, l, 1, 64 + u1)] = q11;
                if (l < 3) {                 // x for layer l+1
                    combh[CIDX(q, l + 1, 0, u0)] = q00;
                    combh[CIDX(q, l + 1, 1, u0)] = q01;
                    combh[CIDX(q, l + 1, 0, u1)] = q10;
                    combh[CIDX(q, l + 1, 1, u1)] = q11;
                } else if (h3f32) {
                    h3f32[rb0 + (long)t * H_ + u0] = h00;
                    h3f32[rb1 + (long)t * H_ + u0] = h01;
                    h3f32[rb0 + (long)t * H_ + u1] = h10;
                    h3f32[rb1 + (long)t * H_ + u1] = h11;
                } else {
                    h3f16[rb0 + (long)t * H_ + u0] = q00;
                    h3f16[rb1 + (long)t * H_ + u0] = q01;
                    h3f16[rb0 + (long)t * H_ + u1] = q10;
                    h3f16[rb1 + (long)t * H_ + u1] = q11;
                }
            }
        }
        if (l == 0 && s + 1 < T_)            // x_0(t+1) -> write parity
            combh[CIDX(q, 0, xrow, xu)] = xnext;
        __syncthreads();
    }
}

// ---------------------------------------------------------------------------
// Output projection: y = GELU(LN(h3) @ W_out1 + b_out1) @ W_out2 + b_out2
// ---------------------------------------------------------------------------
__global__ void __launch_bounds__(256) outproj_kernel(
    const _Float16* __restrict__ h16, const float* __restrict__ h32, int use32,
    const float* __restrict__ g2, const float* __restrict__ b2,
    const float* __restrict__ W1, const float* __restrict__ b1,
    const float* __restrict__ W2, const float* __restrict__ b2o,
    float* __restrict__ y)
{
    __shared__ __align__(16) float W1l[H_ * H_];
    __shared__ __align__(16) float W2l[H_ * 4];
    __shared__ float pg[H_], pb[H_], pb1[H_];
    const int tid = threadIdx.x;
    {
        const float4* s1 = (const float4*)W1;
        float4* d1 = (float4*)W1l;
        for (int i = tid; i < H_ * H_ / 4; i += 256) d1[i] = s1[i];
        if (tid < H_) {
            pg[tid] = g2[tid]; pb[tid] = b2[tid]; pb1[tid] = b1[tid];
            float4 w; w.x = W2[tid*3+0]; w.y = W2[tid*3+1]; w.z = W2[tid*3+2]; w.w = 0.f;
            *(float4*)&W2l[tid * 4] = w;
        }
    }
    __syncthreads();

    const long idx = (long)blockIdx.x * 256 + tid;
    float hv[H_];
    if (use32) {
        const float* hrow = h32 + idx * H_;
        #pragma unroll
        for (int q = 0; q < H_ / 4; ++q) {
            float4 v = *(const float4*)&hrow[q * 4];
            hv[q*4+0] = v.x; hv[q*4+1] = v.y; hv[q*4+2] = v.z; hv[q*4+3] = v.w;
        }
    } else {
        const _Float16* hrow = h16 + idx * H_;
        #pragma unroll
        for (int q = 0; q < H_ / 8; ++q) {
            half8 v = *(const half8*)&hrow[q * 8];
            #pragma unroll
            for (int j = 0; j < 8; ++j) hv[q*8+j] = (float)v[j];
        }
    }
    float mean = 0.f;
    #pragma unroll
    for (int j = 0; j < H_; ++j) mean += hv[j];
    mean *= (1.0f / H_);
    float var = 0.f;
    #pragma unroll
    for (int j = 0; j < H_; ++j) { float dd = hv[j] - mean; var += dd * dd; }
    var *= (1.0f / H_);
    const float inv = rsqrtf(var + EPSF);
    #pragma unroll
    for (int j = 0; j < H_; ++j) hv[j] = (hv[j] - mean) * inv * pg[j] + pb[j];

    float y0 = b2o[0], y1 = b2o[1], y2 = b2o[2];
    for (int ob = 0; ob < H_ / 4; ++ob) {
        float ax = pb1[ob*4+0], ay = pb1[ob*4+1];
        float az = pb1[ob*4+2], aw = pb1[ob*4+3];
        #pragma unroll
        for (int j = 0; j < H_; ++j) {
            float4 w = *(const float4*)&W1l[j * H_ + ob * 4];
            ax += hv[j]*w.x; ay += hv[j]*w.y; az += hv[j]*w.z; aw += hv[j]*w.w;
        }
        ax = gelu_f(ax); ay = gelu_f(ay); az = gelu_f(az); aw = gelu_f(aw);
        float4 wa = *(const float4*)&W2l[(ob*4+0) * 4];
        float4 wb = *(const float4*)&W2l[(ob*4+1) * 4];
        float4 wc = *(const float4*)&W2l[(ob*4+2) * 4];
        float4 wd = *(const float4*)&W2l[(ob*4+3) * 4];
        y0 += ax*wa.x + ay*wb.x + az*wc.x + aw*wd.x;
        y1 += ax*wa.y + ay*wb.y + az*wc.y + aw*wd.y;
        y2 += ax*wa.z + ay*wb.z + az*wc.z + aw*wd.z;
    }
    y[idx * 3 + 0] = y0;
    y[idx * 3 + 1] = y1;
    y[idx * 3 + 2] = y2;
}

// ---------------------------------------------------------------------------
extern "C" void kernel_launch(void* const* d_in, const int* in_sizes, int n_in,
                              void* d_out, int out_size, void* d_ws, size_t ws_size,
                              hipStream_t stream)
{
    const float* sensors = (const float*)d_in[0];
    const float* W_in1   = (const float*)d_in[1];
    const float* b_in1   = (const float*)d_in[2];
    const float* ln1_g   = (const float*)d_in[3];
    const float* ln1_b   = (const float*)d_in[4];
    const float* W_in2   = (const float*)d_in[5];
    const float* b_in2   = (const float*)d_in[6];
    const float* Wg      = (const float*)d_in[7];
    const float* bg      = (const float*)d_in[8];
    const float* ln2_g   = (const float*)d_in[9];
    const float* ln2_b   = (const float*)d_in[10];
    const float* W_out1  = (const float*)d_in[11];
    const float* b_out1  = (const float*)d_in[12];
    const float* W_out2  = (const float*)d_in[13];
    const float* b_out2  = (const float*)d_in[14];
    float* y = (float*)d_out;

    const size_t elems = (size_t)B_ * T_ * H_;
    _Float16* seqh = (_Float16*)d_ws;               // 128 MB fp16 x buffer
    float* h3f32 = nullptr;
    int use32 = 0;
    if (ws_size >= elems * 2 + elems * 4) {
        h3f32 = (float*)((char*)d_ws + elems * 2);
        use32 = 1;
    }

    inproj_kernel<<<B_ * T_ / 256, 256, 0, stream>>>(
        sensors, W_in1, b_in1, ln1_g, ln1_b, W_in2, b_in2, seqh);
    lstm_fused_kernel<<<B_ / 2, 512, 0, stream>>>(Wg, bg, seqh, seqh, h3f32);
    outproj_kernel<<<B_ * T_ / 256, 256, 0, stream>>>(
        seqh, h3f32, use32, ln2_g, ln2_b, W_out1, b_out1, W_out2, b_out2, y);
}

// Round 11
// 3081.872 us; speedup vs baseline: 1.4517x; 1.4517x over previous
//
#include <hip/hip_runtime.h>
#include <math.h>

#define B_   512
#define T_   2048
#define H_   64
#define NS_  32
#define HH_  128   // 2H
#define G4_  256   // 4H
#define EPSF 1e-5f

typedef _Float16 half8 __attribute__((ext_vector_type(8)));
typedef _Float16 h4   __attribute__((ext_vector_type(4)));
typedef float    f32x4 __attribute__((ext_vector_type(4)));

__device__ __forceinline__ float gelu_f(float x) {
    return 0.5f * x * (1.0f + erff(x * 0.70710678118654752440f));
}
__device__ __forceinline__ float sigmoid_f(float x) {
    return 1.0f / (1.0f + __expf(-x));
}
__device__ __forceinline__ float tanh_f(float x) {
    return 1.0f - 2.0f / (__expf(2.0f * x) + 1.0f);
}

// ---------------------------------------------------------------------------
// Input projection -> packed fp16 x-sequence  seqh[B][T][64]
// ---------------------------------------------------------------------------
__global__ void __launch_bounds__(256) inproj_kernel(
    const float* __restrict__ sensors, const float* __restrict__ W1,
    const float* __restrict__ b1, const float* __restrict__ g1,
    const float* __restrict__ bb1, const float* __restrict__ W2,
    const float* __restrict__ b2, _Float16* __restrict__ seqh)
{
    __shared__ __align__(16) float W1l[NS_ * H_];
    __shared__ __align__(16) float W2l[H_ * H_];
    __shared__ float p1[H_], p2[H_], p3[H_], p4[H_];
    const int tid = threadIdx.x;
    {
        const float4* s1 = (const float4*)W1;
        float4* d1 = (float4*)W1l;
        for (int i = tid; i < NS_ * H_ / 4; i += 256) d1[i] = s1[i];
        const float4* s2 = (const float4*)W2;
        float4* d2 = (float4*)W2l;
        for (int i = tid; i < H_ * H_ / 4; i += 256) d2[i] = s2[i];
        if (tid < H_) { p1[tid] = b1[tid]; p2[tid] = g1[tid];
                        p3[tid] = bb1[tid]; p4[tid] = b2[tid]; }
    }
    __syncthreads();

    const long idx = (long)blockIdx.x * 256 + tid;
    const float* srow = sensors + idx * NS_;
    float sv[NS_];
    #pragma unroll
    for (int q = 0; q < NS_ / 4; ++q) {
        float4 v = *(const float4*)&srow[q * 4];
        sv[q*4+0] = v.x; sv[q*4+1] = v.y; sv[q*4+2] = v.z; sv[q*4+3] = v.w;
    }
    float t1[H_];
    #pragma unroll
    for (int jb = 0; jb < H_ / 4; ++jb) {
        float ax = p1[jb*4+0], ay = p1[jb*4+1], az = p1[jb*4+2], aw = p1[jb*4+3];
        #pragma unroll
        for (int k = 0; k < NS_; ++k) {
            float4 w = *(const float4*)&W1l[k * H_ + jb * 4];
            ax += sv[k]*w.x; ay += sv[k]*w.y; az += sv[k]*w.z; aw += sv[k]*w.w;
        }
        t1[jb*4+0] = ax; t1[jb*4+1] = ay; t1[jb*4+2] = az; t1[jb*4+3] = aw;
    }
    float mean = 0.f;
    #pragma unroll
    for (int j = 0; j < H_; ++j) mean += t1[j];
    mean *= (1.0f / H_);
    float var = 0.f;
    #pragma unroll
    for (int j = 0; j < H_; ++j) { float d = t1[j] - mean; var += d * d; }
    var *= (1.0f / H_);
    const float inv = rsqrtf(var + EPSF);
    #pragma unroll
    for (int j = 0; j < H_; ++j) {
        float nv = (t1[j] - mean) * inv * p2[j] + p3[j];
        t1[j] = gelu_f(nv);
    }
    _Float16* orow = seqh + idx * H_;
    for (int ob = 0; ob < H_ / 4; ++ob) {
        float ax = p4[ob*4+0], ay = p4[ob*4+1];
        float az = p4[ob*4+2], aw = p4[ob*4+3];
        #pragma unroll
        for (int j = 0; j < H_; ++j) {
            float4 w = *(const float4*)&W2l[j * H_ + ob * 4];
            ax += t1[j]*w.x; ay += t1[j]*w.y; az += t1[j]*w.z; aw += t1[j]*w.w;
        }
        h4 o; o[0] = (_Float16)ax; o[1] = (_Float16)ay;
              o[2] = (_Float16)az; o[3] = (_Float16)aw;
        *(h4*)&orow[ob * 4] = o;
    }
}

// ---------------------------------------------------------------------------
// Fused 4-layer pipelined LSTM via MFMA (16x16x32 f16, fp32 accum).
// Two-phase step (proven faster than single-barrier in-lane variant):
//   phase 1 (matmul): wave (l,half); A = comb rows, broadcast-read from row
//     lane&1 (rows 2..15 of D are duplicates, never read -> no masking, no
//     zeroing, no swizzle). Bias preloaded into acc. Writes gates to gbuf
//     [l][gate][u][row] as 16-lane float2 across all 32 banks (conflict-free).
//   phase 2 (nonlin): all 512 threads, 1 cell each (l=tid>>7, row, u);
//     reads gbuf at stride-2 (2-way alias = free), writes h (fp16) to comb
//     and h3 (fp16) to global.
//   comb single-buffered [l][row][x|h]; 2 barriers/step make it race-free.
// ---------------------------------------------------------------------------
__global__ void __launch_bounds__(512, 2) lstm_fused_kernel(
    const float* __restrict__ Wg, const float* __restrict__ bg,
    const _Float16* __restrict__ xin,   // [B][T][64] fp16
    _Float16* __restrict__ h3out)       // [B][T][64] fp16
{
    __shared__ __align__(16) _Float16 combh[4][2][HH_];   // 2 KB
    __shared__ __align__(8)  float gbuf[4][4][H_][2];     // 8 KB

    const int tid  = threadIdx.x;
    const int wv   = tid >> 6;
    const int lane = tid & 63;
    const int l    = wv >> 1;               // matmul: layer
    const int half = wv & 1;                // matmul: column half
    const int L    = lane & 15;
    const int kgrp = lane >> 4;             // k-subgroup within fragment

    // ---- weight B-fragments (once) ----
    const float* W = Wg + (size_t)l * HH_ * G4_;
    half8 wf[4][8];                          // [kt][nt]
    #pragma unroll
    for (int kt = 0; kt < 4; ++kt) {
        #pragma unroll
        for (int nt = 0; nt < 8; ++nt) {
            const int col = half * 128 + nt * 16 + L;
            half8 f;
            #pragma unroll
            for (int j = 0; j < 8; ++j)
                f[j] = (_Float16)W[(kt * 32 + kgrp * 8 + j) * G4_ + col];
            wf[kt][nt] = f;
        }
    }
    float ba[8];                             // per-acc bias (col dep. on L only)
    #pragma unroll
    for (int nt = 0; nt < 8; ++nt)
        ba[nt] = bg[l * G4_ + half * 128 + nt * 16 + L];

    // nonlin duty: one cell per thread
    const int nl_l = tid >> 7;
    const int nrow = (tid >> 6) & 1;
    const int u    = tid & 63;
    const long nbase = ((long)(blockIdx.x * 2 + nrow)) * T_ * H_ + u;

    // x-prefetch duty (l==0 waves): 2 waves cover 2 rows x 64 units
    const int  xrow = lane >> 5;
    const int  xu   = half * 32 + (lane & 31);
    const long xbase = ((long)(blockIdx.x * 2 + xrow)) * T_ * H_ + xu;

    // ---- init: zero comb, stage x(0) ----
    for (int i = tid; i < 4 * 2 * HH_ / 2; i += 512) ((float*)combh)[i] = 0.f;
    __syncthreads();
    if (l == 0) combh[0][xrow][xu] = xin[xbase];
    __syncthreads();

    float c_reg = 0.f;

    for (int s = 0; s < T_ + 3; ++s) {
        const bool mact = (s >= l) && (s - l < T_);
        const bool nact = (s >= nl_l) && (s - nl_l < T_);

        _Float16 xnext = (_Float16)0.f;
        if (l == 0 && s + 1 < T_)            // issued early; hides under MFMAs
            xnext = xin[xbase + (long)(s + 1) * H_];

        if (mact) {
            // A-fragments: broadcast from real rows (row = lane&1)
            const _Float16* cp = &combh[l][lane & 1][0];
            half8 af[4];
            #pragma unroll
            for (int kt = 0; kt < 4; ++kt)
                af[kt] = *(const half8*)&cp[kt * 32 + kgrp * 8];

            f32x4 acc[8];
            #pragma unroll
            for (int nt = 0; nt < 8; ++nt)
                acc[nt] = (f32x4){ba[nt], ba[nt], ba[nt], ba[nt]};
            #pragma unroll
            for (int kt = 0; kt < 4; ++kt) {
                #pragma unroll
                for (int nt = 0; nt < 8; ++nt)
                    acc[nt] = __builtin_amdgcn_mfma_f32_16x16x32_f16(
                        af[kt], wf[kt][nt], acc[nt], 0, 0, 0);
            }
            if (lane < 16) {                 // D: col=lane, row=reg (m89 map)
                #pragma unroll
                for (int nt = 0; nt < 8; ++nt) {
                    const int col = half * 128 + nt * 16 + lane;
                    const int g   = col >> 6;
                    const int ug  = col & 63;
                    float2 v; v.x = acc[nt][0]; v.y = acc[nt][1];  // rows 0,1
                    *(float2*)&gbuf[l][g][ug][0] = v;
                }
            }
        }
        __syncthreads();

        if (nact) {
            const int t = s - nl_l;
            const float gi = gbuf[nl_l][0][u][nrow];
            const float gf = gbuf[nl_l][1][u][nrow];
            const float gg = gbuf[nl_l][2][u][nrow];
            const float go = gbuf[nl_l][3][u][nrow];
            c_reg = sigmoid_f(gf) * c_reg + sigmoid_f(gi) * tanh_f(gg);
            const float hn = sigmoid_f(go) * tanh_f(c_reg);
            const _Float16 hh = (_Float16)hn;
            combh[nl_l][nrow][64 + u] = hh;                  // h_l(t)
            if (nl_l < 3) combh[nl_l + 1][nrow][u] = hh;     // x_{l+1}(t)
            else          h3out[nbase + (long)t * H_] = hh;  // h3(t), fp16
        }
        if (l == 0 && s + 1 < T_)
            combh[0][xrow][xu] = xnext;                      // x_0(t+1)
        __syncthreads();
    }
}

// ---------------------------------------------------------------------------
// Output projection: y = GELU(LN(h3) @ W_out1 + b_out1) @ W_out2 + b_out2
// ---------------------------------------------------------------------------
__global__ void __launch_bounds__(256) outproj_kernel(
    const _Float16* __restrict__ h16,
    const float* __restrict__ g2, const float* __restrict__ b2,
    const float* __restrict__ W1, const float* __restrict__ b1,
    const float* __restrict__ W2, const float* __restrict__ b2o,
    float* __restrict__ y)
{
    __shared__ __align__(16) float W1l[H_ * H_];
    __shared__ __align__(16) float W2l[H_ * 4];
    __shared__ float pg[H_], pb[H_], pb1[H_];
    const int tid = threadIdx.x;
    {
        const float4* s1 = (const float4*)W1;
        float4* d1 = (float4*)W1l;
        for (int i = tid; i < H_ * H_ / 4; i += 256) d1[i] = s1[i];
        if (tid < H_) {
            pg[tid] = g2[tid]; pb[tid] = b2[tid]; pb1[tid] = b1[tid];
            float4 w; w.x = W2[tid*3+0]; w.y = W2[tid*3+1]; w.z = W2[tid*3+2]; w.w = 0.f;
            *(float4*)&W2l[tid * 4] = w;
        }
    }
    __syncthreads();

    const long idx = (long)blockIdx.x * 256 + tid;
    const _Float16* hrow = h16 + idx * H_;
    float hv[H_];
    #pragma unroll
    for (int q = 0; q < H_ / 8; ++q) {
        half8 v = *(const half8*)&hrow[q * 8];
        #pragma unroll
        for (int j = 0; j < 8; ++j) hv[q*8+j] = (float)v[j];
    }
    float mean = 0.f;
    #pragma unroll
    for (int j = 0; j < H_; ++j) mean += hv[j];
    mean *= (1.0f / H_);
    float var = 0.f;
    #pragma unroll
    for (int j = 0; j < H_; ++j) { float dd = hv[j] - mean; var += dd * dd; }
    var *= (1.0f / H_);
    const float inv = rsqrtf(var + EPSF);
    #pragma unroll
    for (int j = 0; j < H_; ++j) hv[j] = (hv[j] - mean) * inv * pg[j] + pb[j];

    float y0 = b2o[0], y1 = b2o[1], y2 = b2o[2];
    for (int ob = 0; ob < H_ / 4; ++ob) {
        float ax = pb1[ob*4+0], ay = pb1[ob*4+1];
        float az = pb1[ob*4+2], aw = pb1[ob*4+3];
        #pragma unroll
        for (int j = 0; j < H_; ++j) {
            float4 w = *(const float4*)&W1l[j * H_ + ob * 4];
            ax += hv[j]*w.x; ay += hv[j]*w.y; az += hv[j]*w.z; aw += hv[j]*w.w;
        }
        ax = gelu_f(ax); ay = gelu_f(ay); az = gelu_f(az); aw = gelu_f(aw);
        float4 wa = *(const float4*)&W2l[(ob*4+0) * 4];
        float4 wb = *(const float4*)&W2l[(ob*4+1) * 4];
        float4 wc = *(const float4*)&W2l[(ob*4+2) * 4];
        float4 wd = *(const float4*)&W2l[(ob*4+3) * 4];
        y0 += ax*wa.x + ay*wb.x + az*wc.x + aw*wd.x;
        y1 += ax*wa.y + ay*wb.y + az*wc.y + aw*wd.y;
        y2 += ax*wa.z + ay*wb.z + az*wc.z + aw*wd.z;
    }
    y[idx * 3 + 0] = y0;
    y[idx * 3 + 1] = y1;
    y[idx * 3 + 2] = y2;
}

// ---------------------------------------------------------------------------
extern "C" void kernel_launch(void* const* d_in, const int* in_sizes, int n_in,
                              void* d_out, int out_size, void* d_ws, size_t ws_size,
                              hipStream_t stream)
{
    const float* sensors = (const float*)d_in[0];
    const float* W_in1   = (const float*)d_in[1];
    const float* b_in1   = (const float*)d_in[2];
    const float* ln1_g   = (const float*)d_in[3];
    const float* ln1_b   = (const float*)d_in[4];
    const float* W_in2   = (const float*)d_in[5];
    const float* b_in2   = (const float*)d_in[6];
    const float* Wg      = (const float*)d_in[7];
    const float* bg      = (const float*)d_in[8];
    const float* ln2_g   = (const float*)d_in[9];
    const float* ln2_b   = (const float*)d_in[10];
    const float* W_out1  = (const float*)d_in[11];
    const float* b_out1  = (const float*)d_in[12];
    const float* W_out2  = (const float*)d_in[13];
    const float* b_out2  = (const float*)d_in[14];
    float* y = (float*)d_out;

    const size_t elems = (size_t)B_ * T_ * H_;
    _Float16* seqh = (_Float16*)d_ws;                        // 128 MB x (fp16)
    _Float16* h3   = (_Float16*)((char*)d_ws + elems * 2);   // 128 MB h3 (fp16)

    inproj_kernel<<<B_ * T_ / 256, 256, 0, stream>>>(
        sensors, W_in1, b_in1, ln1_g, ln1_b, W_in2, b_in2, seqh);
    lstm_fused_kernel<<<B_ / 2, 512, 0, stream>>>(Wg, bg, seqh, h3);
    outproj_kernel<<<B_ * T_ / 256, 256, 0, stream>>>(
        h3, ln2_g, ln2_b, W_out1, b_out1, W_out2, b_out2, y);
}